// Round 1
// baseline (458.957 us; speedup 1.0000x reference)
//
#include <hip/hip_runtime.h>
#include <hip/hip_bf16.h>
#include <stdint.h>

#define SEQ   2048
#define DM    4096
#define NH    32
#define NKV   8
#define HD    128
#define DKV   1024   // NKV*HD

typedef __attribute__((ext_vector_type(8))) short bf8_t;   // 8 bf16 (4 VGPR)
typedef __attribute__((ext_vector_type(4))) float f4_t;

__device__ __forceinline__ short f2bf(float f) {
  union { float f; uint32_t u; } v; v.f = f;
  uint32_t r = v.u + 0x7FFFu + ((v.u >> 16) & 1u);
  return (short)(r >> 16);
}
__device__ __forceinline__ float bf2f(short s) {
  union { uint32_t u; float f; } v; v.u = ((uint32_t)(uint16_t)s) << 16;
  return v.f;
}

// CK-style global->LDS async copy, 16B per lane
__device__ __forceinline__ void async_copy16(const void* gsrc, void* ldst) {
  auto g = reinterpret_cast<const __attribute__((address_space(1))) uint32_t*>(
      reinterpret_cast<uintptr_t>(gsrc));
  auto l = reinterpret_cast<__attribute__((address_space(3))) uint32_t*>(
      reinterpret_cast<uintptr_t>(ldst));
  __builtin_amdgcn_global_load_lds(g, l, 16, 0, 0);
}

__device__ __forceinline__ f4_t mfma_bf16(bf8_t a, bf8_t b, f4_t c) {
  return __builtin_amdgcn_mfma_f32_16x16x32_bf16(a, b, c, 0, 0, 0);
}

// ---------------- f32 -> bf16 convert ----------------
__global__ void cvt_bf16_kernel(const float* __restrict__ in, short* __restrict__ out, int n4) {
  const int stride = gridDim.x * blockDim.x;
  for (int i = blockIdx.x * blockDim.x + threadIdx.x; i < n4; i += stride) {
    float4 v = ((const float4*)in)[i];
    short4 o;
    o.x = f2bf(v.x); o.y = f2bf(v.y); o.z = f2bf(v.z); o.w = f2bf(v.w);
    ((short4*)out)[i] = o;
  }
}

// ---------------- GEMM: C = A[M][K] * B[N][K]^T  (B^T layout) ----------------
// MODE 0: single B (wo), f32 output [SEQ][DM] to Cf
// MODE 1: fused QKV over N=6144: cols [0,4096)->Cq bf16, [4096,5120)->Ck bf16,
//         [5120,6144)->Cv transposed bf16 [DKV][SEQ]
template<int MODE>
__global__ __launch_bounds__(256)
void gemm_bt_kernel(const short* __restrict__ A,
                    const short* __restrict__ Bq,
                    const short* __restrict__ Bk,
                    const short* __restrict__ Bv,
                    float* __restrict__ Cf,
                    short* __restrict__ Cq,
                    short* __restrict__ Ck,
                    short* __restrict__ Cv)
{
  __shared__ short Al[128 * 32];
  __shared__ short Bl[128 * 32];
  const int tid  = threadIdx.x;
  const int lane = tid & 63;
  const int wid  = tid >> 6;
  const int wr = wid >> 1, wc = wid & 1;
  const int row0 = blockIdx.y * 128;
  const int col0 = blockIdx.x * 128;

  const short* B; int bcol; int region = 0;
  if (MODE == 0) { B = Bq; bcol = col0; }
  else {
    if (col0 < DM)            { B = Bq; bcol = col0;             region = 0; }
    else if (col0 < DM + DKV) { B = Bk; bcol = col0 - DM;        region = 1; }
    else                      { B = Bv; bcol = col0 - DM - DKV;  region = 2; }
  }

  f4_t acc[4][4];
  #pragma unroll
  for (int i = 0; i < 4; i++)
    #pragma unroll
    for (int j = 0; j < 4; j++) { acc[i][j][0]=0.f; acc[i][j][1]=0.f; acc[i][j][2]=0.f; acc[i][j][3]=0.f; }

  const int cl = lane & 15, kh = lane >> 4;
  const int K = DM;

  for (int k0 = 0; k0 < K; k0 += 32) {
    #pragma unroll
    for (int i = 0; i < 2; ++i) {
      int c = tid + i * 256;                 // chunk id 0..511; row=c>>2, col=(c&3)*8
      async_copy16(&A[(size_t)(row0 + (c >> 2)) * K + k0 + (c & 3) * 8], &Al[c * 8]);
    }
    #pragma unroll
    for (int i = 0; i < 2; ++i) {
      int c = tid + i * 256;
      async_copy16(&B[(size_t)(bcol + (c >> 2)) * K + k0 + (c & 3) * 8], &Bl[c * 8]);
    }
    __syncthreads();

    bf8_t aF[4], bF[4];
    #pragma unroll
    for (int i = 0; i < 4; i++)
      aF[i] = *(const bf8_t*)&Al[(wr * 64 + i * 16 + cl) * 32 + kh * 8];
    #pragma unroll
    for (int i = 0; i < 4; i++)
      bF[i] = *(const bf8_t*)&Bl[(wc * 64 + i * 16 + cl) * 32 + kh * 8];

    #pragma unroll
    for (int mi = 0; mi < 4; mi++)
      #pragma unroll
      for (int ni = 0; ni < 4; ni++)
        acc[mi][ni] = mfma_bf16(aF[mi], bF[ni], acc[mi][ni]);
    __syncthreads();
  }

  // epilogue: C layout col = lane&15, row = (lane>>4)*4 + reg
  const int rb = kh * 4;
  #pragma unroll
  for (int mi = 0; mi < 4; mi++) {
    const int m0 = row0 + wr * 64 + mi * 16 + rb;
    #pragma unroll
    for (int ni = 0; ni < 4; ni++) {
      const int n = col0 + wc * 64 + ni * 16 + cl;
      if (MODE == 0) {
        #pragma unroll
        for (int r = 0; r < 4; r++) Cf[(size_t)(m0 + r) * DM + n] = acc[mi][ni][r];
      } else if (region == 0) {
        #pragma unroll
        for (int r = 0; r < 4; r++) Cq[(size_t)(m0 + r) * DM + n] = f2bf(acc[mi][ni][r]);
      } else if (region == 1) {
        const int nk = n - DM;
        #pragma unroll
        for (int r = 0; r < 4; r++) Ck[(size_t)(m0 + r) * DKV + nk] = f2bf(acc[mi][ni][r]);
      } else {
        const int nv = n - DM - DKV;  // 0..1023 = kv_head*128 + d
        short4 pk;
        pk.x = f2bf(acc[mi][ni][0]); pk.y = f2bf(acc[mi][ni][1]);
        pk.z = f2bf(acc[mi][ni][2]); pk.w = f2bf(acc[mi][ni][3]);
        *(short4*)&Cv[(size_t)nv * SEQ + m0] = pk;
      }
    }
  }
}

// ---------------- RoPE in-place on Q and K (bf16) ----------------
__global__ void rope_kernel(short* __restrict__ Qb, short* __restrict__ Kb,
                            const float* __restrict__ fcos, const float* __restrict__ fsin)
{
  const int NQP = SEQ * (DM / 2);   // 2048*2048 q pairs
  const int NKP = SEQ * (DKV / 2);  // 2048*512 k pairs
  int idx = blockIdx.x * blockDim.x + threadIdx.x;
  if (idx >= NQP + NKP) return;
  short* T; int s, p, rowlen;
  if (idx < NQP) { T = Qb; s = idx >> 11; p = idx & 2047; rowlen = DM; }
  else { int j = idx - NQP; T = Kb; s = j >> 9; p = j & 511; rowlen = DKV; }
  const int h = p >> 6, i = p & 63;
  const float c  = fcos[s * 64 + i];
  const float sn = fsin[s * 64 + i];
  const size_t base = (size_t)s * rowlen + h * HD + 2 * i;
  const float e = bf2f(T[base]), o = bf2f(T[base + 1]);
  T[base]     = f2bf(e * c - o * sn);
  T[base + 1] = f2bf(e * sn + o * c);
}

// ---------------- Flash attention (causal, GQA) ----------------
// grid: (SEQ/64, NH); 256 threads = 4 waves, each wave owns 16 q-rows.
__global__ __launch_bounds__(256)
void flash_kernel(const short* __restrict__ Qb,  // [SEQ][DM], roped
                  const short* __restrict__ Kb,  // [SEQ][DKV], roped
                  const short* __restrict__ Vt,  // [DKV][SEQ] transposed
                  short* __restrict__ Ob)        // [SEQ][DM]
{
  const int h   = blockIdx.y;
  const int q0  = blockIdx.x * 64;
  const int hkv = h >> 2;
  const int tid = threadIdx.x, lane = tid & 63, wid = tid >> 6;

  __shared__ short Kl[64 * 136];   // K tile, padded stride (2-way banks, 16B aligned rows)
  __shared__ short Vl[128 * 72];   // V^T tile (rows = d), padded
  __shared__ short Pl[4 * 16 * 72]; // per-wave P staging

  const int cl = lane & 15, kh = lane >> 4, rb = kh * 4;
  const float scale = 0.08838834764831845f; // 1/sqrt(128)

  // Q fragments in registers (A-frag: row=lane&15, k=kh*8+j)
  bf8_t qF[4];
  {
    const int qrow = q0 + wid * 16 + cl;
    #pragma unroll
    for (int k = 0; k < 4; k++)
      qF[k] = *(const bf8_t*)&Qb[(size_t)qrow * DM + h * HD + k * 32 + kh * 8];
  }

  f4_t accO[8];
  #pragma unroll
  for (int nd = 0; nd < 8; nd++) { accO[nd][0]=0.f; accO[nd][1]=0.f; accO[nd][2]=0.f; accO[nd][3]=0.f; }
  float m_r[4] = {-INFINITY, -INFINITY, -INFINITY, -INFINITY};
  float l_r[4] = {0.f, 0.f, 0.f, 0.f};

  const int nt = (q0 >> 6) + 1;
  for (int t = 0; t < nt; ++t) {
    const int kv0 = t * 64;
    // stage K tile: 64 rows x 128, 1024 16B chunks
    #pragma unroll
    for (int i = 0; i < 4; i++) {
      int c = tid + i * 256;
      int r = c >> 4, co = (c & 15) * 8;
      *(int4*)&Kl[r * 136 + co] = *(const int4*)&Kb[(size_t)(kv0 + r) * DKV + hkv * HD + co];
    }
    // stage V^T tile: 128 rows (d) x 64 (kv)
    #pragma unroll
    for (int i = 0; i < 4; i++) {
      int c = tid + i * 256;
      int r = c >> 3, co = (c & 7) * 8;
      *(int4*)&Vl[r * 72 + co] = *(const int4*)&Vt[(size_t)(hkv * HD + r) * SEQ + kv0 + co];
    }
    __syncthreads();

    // S = Q K^T : 16x64 per wave
    f4_t accS[4];
    #pragma unroll
    for (int ni = 0; ni < 4; ni++) { accS[ni][0]=0.f; accS[ni][1]=0.f; accS[ni][2]=0.f; accS[ni][3]=0.f; }
    #pragma unroll
    for (int ni = 0; ni < 4; ni++)
      #pragma unroll
      for (int k = 0; k < 4; k++) {
        bf8_t kf = *(const bf8_t*)&Kl[(ni * 16 + cl) * 136 + k * 32 + kh * 8];
        accS[ni] = mfma_bf16(qF[k], kf, accS[ni]);
      }

    const bool last = (t == nt - 1);
    float sc[4][4];
    #pragma unroll
    for (int ni = 0; ni < 4; ni++)
      #pragma unroll
      for (int r = 0; r < 4; r++) {
        float v = accS[ni][r] * scale;
        if (last) {
          const int col = kv0 + ni * 16 + cl;
          const int row = q0 + wid * 16 + rb + r;
          if (col > row) v = -3.0e38f;
        }
        sc[ni][r] = v;
      }

    // online softmax: row stats live in the 16-lane group (xor 1,2,4,8)
    float mnew[4], corr[4];
    #pragma unroll
    for (int r = 0; r < 4; r++) {
      float v = fmaxf(fmaxf(sc[0][r], sc[1][r]), fmaxf(sc[2][r], sc[3][r]));
      v = fmaxf(v, __shfl_xor(v, 1));
      v = fmaxf(v, __shfl_xor(v, 2));
      v = fmaxf(v, __shfl_xor(v, 4));
      v = fmaxf(v, __shfl_xor(v, 8));
      mnew[r] = fmaxf(m_r[r], v);
      corr[r] = __expf(m_r[r] - mnew[r]);
      m_r[r] = mnew[r];
    }
    #pragma unroll
    for (int ni = 0; ni < 4; ni++)
      #pragma unroll
      for (int r = 0; r < 4; r++)
        sc[ni][r] = __expf(sc[ni][r] - mnew[r]);
    #pragma unroll
    for (int r = 0; r < 4; r++) {
      float v = sc[0][r] + sc[1][r] + sc[2][r] + sc[3][r];
      v += __shfl_xor(v, 1); v += __shfl_xor(v, 2);
      v += __shfl_xor(v, 4); v += __shfl_xor(v, 8);
      l_r[r] = l_r[r] * corr[r] + v;
    }
    #pragma unroll
    for (int nd = 0; nd < 8; nd++)
      #pragma unroll
      for (int r = 0; r < 4; r++) accO[nd][r] *= corr[r];

    // P -> bf16 -> LDS (per-wave region), then PV
    #pragma unroll
    for (int ni = 0; ni < 4; ni++)
      #pragma unroll
      for (int r = 0; r < 4; r++)
        Pl[(wid * 16 + rb + r) * 72 + ni * 16 + cl] = f2bf(sc[ni][r]);

    bf8_t pa[2];
    #pragma unroll
    for (int x = 0; x < 2; x++)
      pa[x] = *(const bf8_t*)&Pl[(wid * 16 + cl) * 72 + x * 32 + kh * 8];
    #pragma unroll
    for (int nd = 0; nd < 8; nd++)
      #pragma unroll
      for (int x = 0; x < 2; x++) {
        bf8_t vf = *(const bf8_t*)&Vl[(nd * 16 + cl) * 72 + x * 32 + kh * 8];
        accO[nd] = mfma_bf16(pa[x], vf, accO[nd]);
      }
    __syncthreads();
  }

  float rinv[4];
  #pragma unroll
  for (int r = 0; r < 4; r++) rinv[r] = 1.0f / l_r[r];
  #pragma unroll
  for (int nd = 0; nd < 8; nd++)
    #pragma unroll
    for (int r = 0; r < 4; r++)
      Ob[(size_t)(q0 + wid * 16 + rb + r) * DM + h * HD + nd * 16 + cl] =
          f2bf(accO[nd][r] * rinv[r]);
}

// ---------------- launch ----------------
extern "C" void kernel_launch(void* const* d_in, const int* in_sizes, int n_in,
                              void* d_out, int out_size, void* d_ws, size_t ws_size,
                              hipStream_t stream)
{
  const float* x    = (const float*)d_in[0];
  const float* fcos = (const float*)d_in[1];
  const float* fsin = (const float*)d_in[2];
  const float* wq   = (const float*)d_in[3];
  const float* wk   = (const float*)d_in[4];
  const float* wv   = (const float*)d_in[5];
  const float* wo   = (const float*)d_in[6];
  float* out = (float*)d_out;

  char* p = (char*)d_ws;
  short* xb  = (short*)p; p += (size_t)SEQ * DM * 2;
  short* wqb = (short*)p; p += (size_t)DM * DM * 2;
  short* wkb = (short*)p; p += (size_t)DKV * DM * 2;
  short* wvb = (short*)p; p += (size_t)DKV * DM * 2;
  short* wob = (short*)p; p += (size_t)DM * DM * 2;
  short* Qb  = (short*)p; p += (size_t)SEQ * DM * 2;
  short* Kb  = (short*)p; p += (size_t)SEQ * DKV * 2;
  short* Vt  = (short*)p; p += (size_t)DKV * SEQ * 2;
  short* Ab  = (short*)p; p += (size_t)SEQ * DM * 2;

  cvt_bf16_kernel<<<1024, 256, 0, stream>>>(x,  xb,  SEQ * DM / 4);
  cvt_bf16_kernel<<<2048, 256, 0, stream>>>(wq, wqb, DM * DM / 4);
  cvt_bf16_kernel<<<1024, 256, 0, stream>>>(wk, wkb, DKV * DM / 4);
  cvt_bf16_kernel<<<1024, 256, 0, stream>>>(wv, wvb, DKV * DM / 4);
  cvt_bf16_kernel<<<2048, 256, 0, stream>>>(wo, wob, DM * DM / 4);

  gemm_bt_kernel<1><<<dim3(48, 16), 256, 0, stream>>>(xb, wqb, wkb, wvb,
                                                      nullptr, Qb, Kb, Vt);
  rope_kernel<<<20480, 256, 0, stream>>>(Qb, Kb, fcos, fsin);
  flash_kernel<<<dim3(SEQ / 64, NH), 256, 0, stream>>>(Qb, Kb, Vt, Ab);
  gemm_bt_kernel<0><<<dim3(32, 16), 256, 0, stream>>>(Ab, wob, nullptr, nullptr,
                                                      out, nullptr, nullptr, nullptr);
}

// Round 3
// 344.503 us; speedup vs baseline: 1.3322x; 1.3322x over previous
//
#include <hip/hip_runtime.h>
#include <hip/hip_bf16.h>
#include <stdint.h>

#define SEQ   2048
#define DM    4096
#define NH    32
#define NKV   8
#define HD    128
#define DKV   1024   // NKV*HD

typedef __attribute__((ext_vector_type(8))) short bf8_t;   // 8 bf16 (4 VGPR)
typedef __attribute__((ext_vector_type(4))) float f4_t;
typedef __attribute__((ext_vector_type(16))) float f16x;

__device__ __forceinline__ short f2bf(float f) {
  union { float f; uint32_t u; } v; v.f = f;
  uint32_t r = v.u + 0x7FFFu + ((v.u >> 16) & 1u);
  return (short)(r >> 16);
}
__device__ __forceinline__ float bf2f(short s) {
  union { uint32_t u; float f; } v; v.u = ((uint32_t)(uint16_t)s) << 16;
  return v.f;
}
__device__ __forceinline__ uint32_t cvtpk(float lo, float hi) {
  uint32_t r;
  asm("v_cvt_pk_bf16_f32 %0, %1, %2" : "=v"(r) : "v"(lo), "v"(hi));
  return r;
}

// CK-style global->LDS async copy, 16B per lane (lds addr must be lane-linear)
__device__ __forceinline__ void async_copy16(const void* gsrc, void* ldst) {
  auto g = reinterpret_cast<const __attribute__((address_space(1))) uint32_t*>(
      reinterpret_cast<uintptr_t>(gsrc));
  auto l = reinterpret_cast<__attribute__((address_space(3))) uint32_t*>(
      reinterpret_cast<uintptr_t>(ldst));
  __builtin_amdgcn_global_load_lds(g, l, 16, 0, 0);
}

__device__ __forceinline__ f4_t mfma16(bf8_t a, bf8_t b, f4_t c) {
  return __builtin_amdgcn_mfma_f32_16x16x32_bf16(a, b, c, 0, 0, 0);
}
__device__ __forceinline__ f16x mfma32(bf8_t a, bf8_t b, f16x c) {
  return __builtin_amdgcn_mfma_f32_32x32x16_bf16(a, b, c, 0, 0, 0);
}

// ---------------- f32 -> bf16 convert ----------------
__global__ void cvt_bf16_kernel(const float* __restrict__ in, short* __restrict__ out, int n4) {
  const int stride = gridDim.x * blockDim.x;
  for (int i = blockIdx.x * blockDim.x + threadIdx.x; i < n4; i += stride) {
    float4 v = ((const float4*)in)[i];
    short4 o;
    o.x = f2bf(v.x); o.y = f2bf(v.y); o.z = f2bf(v.z); o.w = f2bf(v.w);
    ((short4*)out)[i] = o;
  }
}

// ---------------- GEMM: C = A[M][K] * B[N][K]^T  (B^T layout) ----------------
template<int MODE>
__global__ __launch_bounds__(256)
void gemm_bt_kernel(const short* __restrict__ A,
                    const short* __restrict__ Bq,
                    const short* __restrict__ Bk,
                    const short* __restrict__ Bv,
                    float* __restrict__ Cf,
                    short* __restrict__ Cq,
                    short* __restrict__ Ck,
                    short* __restrict__ Cv)
{
  __shared__ short Al[128 * 32];
  __shared__ short Bl[128 * 32];
  const int tid  = threadIdx.x;
  const int lane = tid & 63;
  const int wid  = tid >> 6;
  const int wr = wid >> 1, wc = wid & 1;
  const int row0 = blockIdx.y * 128;
  const int col0 = blockIdx.x * 128;

  const short* B; int bcol; int region = 0;
  if (MODE == 0) { B = Bq; bcol = col0; }
  else {
    if (col0 < DM)            { B = Bq; bcol = col0;             region = 0; }
    else if (col0 < DM + DKV) { B = Bk; bcol = col0 - DM;        region = 1; }
    else                      { B = Bv; bcol = col0 - DM - DKV;  region = 2; }
  }

  f4_t acc[4][4];
  #pragma unroll
  for (int i = 0; i < 4; i++)
    #pragma unroll
    for (int j = 0; j < 4; j++) { acc[i][j][0]=0.f; acc[i][j][1]=0.f; acc[i][j][2]=0.f; acc[i][j][3]=0.f; }

  const int cl = lane & 15, kh = lane >> 4;
  const int K = DM;

  for (int k0 = 0; k0 < K; k0 += 32) {
    #pragma unroll
    for (int i = 0; i < 2; ++i) {
      int c = tid + i * 256;
      async_copy16(&A[(size_t)(row0 + (c >> 2)) * K + k0 + (c & 3) * 8], &Al[c * 8]);
    }
    #pragma unroll
    for (int i = 0; i < 2; ++i) {
      int c = tid + i * 256;
      async_copy16(&B[(size_t)(bcol + (c >> 2)) * K + k0 + (c & 3) * 8], &Bl[c * 8]);
    }
    __syncthreads();

    bf8_t aF[4], bF[4];
    #pragma unroll
    for (int i = 0; i < 4; i++)
      aF[i] = *(const bf8_t*)&Al[(wr * 64 + i * 16 + cl) * 32 + kh * 8];
    #pragma unroll
    for (int i = 0; i < 4; i++)
      bF[i] = *(const bf8_t*)&Bl[(wc * 64 + i * 16 + cl) * 32 + kh * 8];

    #pragma unroll
    for (int mi = 0; mi < 4; mi++)
      #pragma unroll
      for (int ni = 0; ni < 4; ni++)
        acc[mi][ni] = mfma16(aF[mi], bF[ni], acc[mi][ni]);
    __syncthreads();
  }

  const int rb = kh * 4;
  #pragma unroll
  for (int mi = 0; mi < 4; mi++) {
    const int m0 = row0 + wr * 64 + mi * 16 + rb;
    #pragma unroll
    for (int ni = 0; ni < 4; ni++) {
      const int n = col0 + wc * 64 + ni * 16 + cl;
      if (MODE == 0) {
        #pragma unroll
        for (int r = 0; r < 4; r++) Cf[(size_t)(m0 + r) * DM + n] = acc[mi][ni][r];
      } else if (region == 0) {
        #pragma unroll
        for (int r = 0; r < 4; r++) Cq[(size_t)(m0 + r) * DM + n] = f2bf(acc[mi][ni][r]);
      } else if (region == 1) {
        const int nk = n - DM;
        #pragma unroll
        for (int r = 0; r < 4; r++) Ck[(size_t)(m0 + r) * DKV + nk] = f2bf(acc[mi][ni][r]);
      } else {
        const int nv = n - DM - DKV;
        short4 pk;
        pk.x = f2bf(acc[mi][ni][0]); pk.y = f2bf(acc[mi][ni][1]);
        pk.z = f2bf(acc[mi][ni][2]); pk.w = f2bf(acc[mi][ni][3]);
        *(short4*)&Cv[(size_t)nv * SEQ + m0] = pk;
      }
    }
  }
}

// ---------------- RoPE in-place on Q and K (bf16) ----------------
__global__ void rope_kernel(short* __restrict__ Qb, short* __restrict__ Kb,
                            const float* __restrict__ fcos, const float* __restrict__ fsin)
{
  const int NQP = SEQ * (DM / 2);
  const int NKP = SEQ * (DKV / 2);
  int idx = blockIdx.x * blockDim.x + threadIdx.x;
  if (idx >= NQP + NKP) return;
  short* T; int s, p, rowlen;
  if (idx < NQP) { T = Qb; s = idx >> 11; p = idx & 2047; rowlen = DM; }
  else { int j = idx - NQP; T = Kb; s = j >> 9; p = j & 511; rowlen = DKV; }
  const int h = p >> 6, i = p & 63;
  const float c  = fcos[s * 64 + i];
  const float sn = fsin[s * 64 + i];
  const size_t base = (size_t)s * rowlen + h * HD + 2 * i;
  const float e = bf2f(T[base]), o = bf2f(T[base + 1]);
  T[base]     = f2bf(e * c - o * sn);
  T[base + 1] = f2bf(e * sn + o * c);
}

// ---------------- Flash attention v2 (causal, GQA, 32x32 swapped MFMA) -------
// Q-tile 128 (4 waves x 32 rows), KV-tile 64, dbuf K/V, O^T accumulation.
// LDS layouts (bf16): Kl [64 kv][128 d] row-major, 16B chunks XOR-swizzled by
// chunk ^= row&7. Vl = V^T [128 d][64 kv], chunks swizzled likewise.

__device__ __forceinline__ void flash_stage(const short* __restrict__ Kb,
                                            const short* __restrict__ Vt,
                                            short* Kl, short* Vl,
                                            int kv0, int hkv, int wid, int lane)
{
  #pragma unroll
  for (int i = 0; i < 4; ++i) {                 // K: 64 rows x 16 chunks
    int c = wid * 256 + i * 64 + lane;
    int row = c >> 4, pos = c & 15;
    int dc = pos ^ (row & 7);                   // inverse-swizzled source chunk
    async_copy16(&Kb[(size_t)(kv0 + row) * DKV + hkv * HD + dc * 8], &Kl[c * 8]);
  }
  #pragma unroll
  for (int i = 0; i < 4; ++i) {                 // V^T: 128 rows x 8 chunks
    int c = wid * 256 + i * 64 + lane;
    int row = c >> 3, pos = c & 7;
    int kc = pos ^ (row & 7);
    async_copy16(&Vt[(size_t)(hkv * HD + row) * SEQ + kv0 + kc * 8], &Vl[c * 8]);
  }
}

union U4B8 { uint32_t w[4]; bf8_t v; };

__device__ __forceinline__ void flash_compute(const short* __restrict__ Kl,
                                              const short* __restrict__ Vl,
                                              const bf8_t* qF, f16x* accO,
                                              float& m_run, float& l_run,
                                              int kv0, int qw0, int c31, int hi)
{
  const float scale = 0.08838834764831845f;  // 1/sqrt(128)

  // ---- S^T = K * Q^T : D[i=kv][j=q], lane holds q-col c31, 16 kv rows/half
  f16x accS[2];
  #pragma unroll
  for (int nu = 0; nu < 2; ++nu) {
    #pragma unroll
    for (int r = 0; r < 16; ++r) accS[nu][r] = 0.f;
  }
  #pragma unroll
  for (int nu = 0; nu < 2; ++nu) {
    const int row = nu * 32 + c31, rx = row & 7;
    #pragma unroll
    for (int s = 0; s < 8; ++s) {
      const int pos = (2 * s + hi) ^ rx;        // chunk 0..15 (XOR low 3 bits)
      bf8_t kf = *(const bf8_t*)&Kl[row * 128 + pos * 8];
      accS[nu] = mfma32(kf, qF[s], accS[nu]);
    }
  }

  // ---- causal mask (only near-diagonal tiles)
  if (kv0 + 63 > qw0) {
    const int q_abs = qw0 + c31;
    #pragma unroll
    for (int nu = 0; nu < 2; ++nu)
      #pragma unroll
      for (int r = 0; r < 16; ++r) {
        const int kv_abs = kv0 + 32 * nu + (r & 3) + 8 * (r >> 2) + 4 * hi;
        if (kv_abs > q_abs) accS[nu][r] = -3.0e38f;
      }
  }

  // ---- row max (31 local + xor32), defer-max rescale (THR=8)
  float rm = -3.0e38f;
  #pragma unroll
  for (int nu = 0; nu < 2; ++nu)
    #pragma unroll
    for (int r = 0; r < 16; ++r) rm = fmaxf(rm, accS[nu][r]);
  rm = fmaxf(rm, __shfl_xor(rm, 32));
  const float pmax = rm * scale;
  if (!__all(pmax - m_run <= 8.0f)) {
    const float mnew = fmaxf(m_run, pmax);
    const float corr = __expf(m_run - mnew);
    m_run = mnew;
    l_run *= corr;
    #pragma unroll
    for (int dt = 0; dt < 4; ++dt)
      #pragma unroll
      for (int r = 0; r < 16; ++r) accO[dt][r] *= corr;
  }

  // ---- P = exp(S*scale - m), pack quads to bf16 pairs, row-sum
  float tsum = 0.f;
  uint32_t u[8][2];
  #pragma unroll
  for (int m = 0; m < 8; ++m) {
    const int nu = m >> 2, rb = 4 * (m & 3);
    float p0 = __expf(fmaf(accS[nu][rb + 0], scale, -m_run));
    float p1 = __expf(fmaf(accS[nu][rb + 1], scale, -m_run));
    float p2 = __expf(fmaf(accS[nu][rb + 2], scale, -m_run));
    float p3 = __expf(fmaf(accS[nu][rb + 3], scale, -m_run));
    tsum += (p0 + p1) + (p2 + p3);
    u[m][0] = cvtpk(p0, p1);
    u[m][1] = cvtpk(p2, p3);
  }
  l_run += tsum + __shfl_xor(tsum, 32);

  // ---- build P^T B-fragments in-register (xor32 half exchange).
  // Lane (q=c31, hi) slot ks needs kv = ks*16 + hi*8 + j:
  //   j=0..3 from hi_src=0's group u[2ks+hi], j=4..7 from hi_src=1's u[2ks+hi]
  // => keep own u[2ks+hi], PASS own u[2ks+(hi^1)] to partner (it needs group
  //    index matching ITS hi). Static indexing via hi-ternaries (no scratch).
  bf8_t pa[4];
  #pragma unroll
  for (int ks = 0; ks < 4; ++ks) {
    const uint32_t a0 = u[2 * ks][0],     a1 = u[2 * ks][1];      // even group
    const uint32_t b0 = u[2 * ks + 1][0], b1 = u[2 * ks + 1][1];  // odd group
    const uint32_t mp0 = hi ? a0 : b0, mp1 = hi ? a1 : b1;        // presented
    const uint32_t s0 = __shfl_xor(mp0, 32), s1 = __shfl_xor(mp1, 32);
    U4B8 f;
    f.w[0] = hi ? s0 : a0;   // j=0,1
    f.w[1] = hi ? s1 : a1;   // j=2,3
    f.w[2] = hi ? b0 : s0;   // j=4,5
    f.w[3] = hi ? b1 : s1;   // j=6,7
    pa[ks] = f.v;
  }

  // ---- O^T += V^T * P^T : D[i=d][j=q]
  #pragma unroll
  for (int dt = 0; dt < 4; ++dt) {
    const int row = dt * 32 + c31, rx = row & 7;
    #pragma unroll
    for (int ks = 0; ks < 4; ++ks) {
      const int pos = (2 * ks + hi) ^ rx;       // chunk 0..7
      bf8_t vf = *(const bf8_t*)&Vl[row * 64 + pos * 8];
      accO[dt] = mfma32(vf, pa[ks], accO[dt]);
    }
  }
}

__global__ __launch_bounds__(256, 2)
void flash_kernel(const short* __restrict__ Qb,  // [SEQ][DM], roped
                  const short* __restrict__ Kb,  // [SEQ][DKV], roped
                  const short* __restrict__ Vt,  // [DKV][SEQ] transposed
                  short* __restrict__ Ob)        // [SEQ][DM]
{
  __shared__ short Kl0[64 * 128], Kl1[64 * 128];
  __shared__ short Vl0[128 * 64], Vl1[128 * 64];

  const int tid = threadIdx.x, lane = tid & 63, wid = tid >> 6;
  const int c31 = lane & 31, hi = lane >> 5;

  // balanced pairing: blocks b and b+256 -> same head, q-tiles p and 15-p
  const int b = blockIdx.x;
  const int pairid = b & 255, halfsel = b >> 8;
  const int h = pairid >> 3, p = pairid & 7;
  const int qt = halfsel ? (15 - p) : p;
  const int q0 = qt * 128;
  const int hkv = h >> 2;
  const int qw0 = q0 + wid * 32;

  // Q B-fragments in registers: Q[q=c31][k-slice s], 16B each
  bf8_t qF[8];
  {
    const size_t qb = (size_t)(qw0 + c31) * DM + h * HD + hi * 8;
    #pragma unroll
    for (int s = 0; s < 8; ++s) qF[s] = *(const bf8_t*)&Qb[qb + s * 16];
  }

  f16x accO[4];
  #pragma unroll
  for (int dt = 0; dt < 4; ++dt)
    #pragma unroll
    for (int r = 0; r < 16; ++r) accO[dt][r] = 0.f;
  float m_run = -INFINITY, l_run = 0.f;

  const int nt = (q0 >> 6) + 2;                 // even, 2..32

  flash_stage(Kb, Vt, Kl0, Vl0, 0, hkv, wid, lane);
  __syncthreads();
  for (int t = 0; t < nt; t += 2) {
    flash_stage(Kb, Vt, Kl1, Vl1, (t + 1) * 64, hkv, wid, lane);
    if (t * 64 <= qw0 + 31)
      flash_compute(Kl0, Vl0, qF, accO, m_run, l_run, t * 64, qw0, c31, hi);
    __syncthreads();
    if (t + 2 < nt) flash_stage(Kb, Vt, Kl0, Vl0, (t + 2) * 64, hkv, wid, lane);
    if ((t + 1) * 64 <= qw0 + 31)
      flash_compute(Kl1, Vl1, qF, accO, m_run, l_run, (t + 1) * 64, qw0, c31, hi);
    __syncthreads();
  }

  // ---- epilogue: normalize, transpose O^T->O via LDS (reuse K buffers)
  short* Ol = (wid < 2) ? &Kl0[wid * 4096] : &Kl1[(wid - 2) * 4096];
  const float oinv = 1.0f / l_run;
  #pragma unroll
  for (int dt = 0; dt < 4; ++dt)
    #pragma unroll
    for (int w = 0; w < 8; ++w) {
      const int r = 2 * w;
      const int d0 = (r & 3) + 8 * (r >> 2) + 4 * hi + dt * 32;
      const uint32_t pk = cvtpk(accO[dt][r] * oinv, accO[dt][r + 1] * oinv);
      const int pos = (d0 >> 3) ^ (c31 & 7);
      *(uint32_t*)&Ol[c31 * 128 + pos * 8 + (d0 & 7)] = pk;
    }
  __syncthreads();  // own-wave region, but barrier is the safe write->read fence
  const int rowq = lane >> 1;
  #pragma unroll
  for (int i = 0; i < 8; ++i) {
    const int dc = (lane & 1) * 8 + i;
    const int pos = dc ^ (rowq & 7);
    int4 v = *(const int4*)&Ol[rowq * 128 + pos * 8];
    *(int4*)&Ob[(size_t)(q0 + wid * 32 + rowq) * DM + h * HD + dc * 8] = v;
  }
}

// ---------------- launch ----------------
extern "C" void kernel_launch(void* const* d_in, const int* in_sizes, int n_in,
                              void* d_out, int out_size, void* d_ws, size_t ws_size,
                              hipStream_t stream)
{
  const float* x    = (const float*)d_in[0];
  const float* fcos = (const float*)d_in[1];
  const float* fsin = (const float*)d_in[2];
  const float* wq   = (const float*)d_in[3];
  const float* wk   = (const float*)d_in[4];
  const float* wv   = (const float*)d_in[5];
  const float* wo   = (const float*)d_in[6];
  float* out = (float*)d_out;

  char* p = (char*)d_ws;
  short* xb  = (short*)p; p += (size_t)SEQ * DM * 2;
  short* wqb = (short*)p; p += (size_t)DM * DM * 2;
  short* wkb = (short*)p; p += (size_t)DKV * DM * 2;
  short* wvb = (short*)p; p += (size_t)DKV * DM * 2;
  short* wob = (short*)p; p += (size_t)DM * DM * 2;
  short* Qb  = (short*)p; p += (size_t)SEQ * DM * 2;
  short* Kb  = (short*)p; p += (size_t)SEQ * DKV * 2;
  short* Vt  = (short*)p; p += (size_t)DKV * SEQ * 2;
  short* Ab  = (short*)p; p += (size_t)SEQ * DM * 2;

  cvt_bf16_kernel<<<1024, 256, 0, stream>>>(x,  xb,  SEQ * DM / 4);
  cvt_bf16_kernel<<<2048, 256, 0, stream>>>(wq, wqb, DM * DM / 4);
  cvt_bf16_kernel<<<1024, 256, 0, stream>>>(wk, wkb, DKV * DM / 4);
  cvt_bf16_kernel<<<1024, 256, 0, stream>>>(wv, wvb, DKV * DM / 4);
  cvt_bf16_kernel<<<2048, 256, 0, stream>>>(wo, wob, DM * DM / 4);

  gemm_bt_kernel<1><<<dim3(48, 16), 256, 0, stream>>>(xb, wqb, wkb, wvb,
                                                      nullptr, Qb, Kb, Vt);
  rope_kernel<<<20480, 256, 0, stream>>>(Qb, Kb, fcos, fsin);
  flash_kernel<<<512, 256, 0, stream>>>(Qb, Kb, Vt, Ab);
  gemm_bt_kernel<0><<<dim3(32, 16), 256, 0, stream>>>(Ab, wob, nullptr, nullptr,
                                                      out, nullptr, nullptr, nullptr);
}

// Round 4
// 289.833 us; speedup vs baseline: 1.5835x; 1.1886x over previous
//
#include <hip/hip_runtime.h>
#include <hip/hip_bf16.h>
#include <stdint.h>

#define SEQ   2048
#define DM    4096
#define NH    32
#define NKV   8
#define HD    128
#define DKV   1024   // NKV*HD

typedef __attribute__((ext_vector_type(8))) short bf8_t;   // 8 bf16 (4 VGPR)
typedef __attribute__((ext_vector_type(4))) float f4_t;
typedef __attribute__((ext_vector_type(16))) float f16x;

__device__ __forceinline__ short f2bf(float f) {
  union { float f; uint32_t u; } v; v.f = f;
  uint32_t r = v.u + 0x7FFFu + ((v.u >> 16) & 1u);
  return (short)(r >> 16);
}
__device__ __forceinline__ float bf2f(short s) {
  union { uint32_t u; float f; } v; v.u = ((uint32_t)(uint16_t)s) << 16;
  return v.f;
}
__device__ __forceinline__ uint32_t cvtpk(float lo, float hi) {
  uint32_t r;
  asm("v_cvt_pk_bf16_f32 %0, %1, %2" : "=v"(r) : "v"(lo), "v"(hi));
  return r;
}

// CK-style global->LDS async copy, 16B per lane (lds addr must be lane-linear)
__device__ __forceinline__ void async_copy16(const void* gsrc, void* ldst) {
  auto g = reinterpret_cast<const __attribute__((address_space(1))) uint32_t*>(
      reinterpret_cast<uintptr_t>(gsrc));
  auto l = reinterpret_cast<__attribute__((address_space(3))) uint32_t*>(
      reinterpret_cast<uintptr_t>(ldst));
  __builtin_amdgcn_global_load_lds(g, l, 16, 0, 0);
}

__device__ __forceinline__ f4_t mfma16(bf8_t a, bf8_t b, f4_t c) {
  return __builtin_amdgcn_mfma_f32_16x16x32_bf16(a, b, c, 0, 0, 0);
}
__device__ __forceinline__ f16x mfma32(bf8_t a, bf8_t b, f16x c) {
  return __builtin_amdgcn_mfma_f32_32x32x16_bf16(a, b, c, 0, 0, 0);
}

// ---------------- fused f32 -> bf16 convert (x, wq, wk, wv, wo) ----------------
// Output bf16 regions are contiguous at d_ws start in this exact order.
__global__ void cvt_all_kernel(const float* __restrict__ x,
                               const float* __restrict__ wq,
                               const float* __restrict__ wk,
                               const float* __restrict__ wv,
                               const float* __restrict__ wo,
                               short* __restrict__ out)
{
  // region sizes in float4 units
  const int E0 = SEQ * DM / 4;                 // x     : 2097152
  const int E1 = E0 + DM * DM / 4;             // wq    : 6291456
  const int E2 = E1 + DKV * DM / 4;            // wk    : 7340032
  const int E3 = E2 + DKV * DM / 4;            // wv    : 8388608
  const int E4 = E3 + DM * DM / 4;             // wo    : 12582912
  const int stride = gridDim.x * blockDim.x;
  for (int i = blockIdx.x * blockDim.x + threadIdx.x; i < E4; i += stride) {
    const float4* src; int off;
    if (i < E0)      { src = (const float4*)x;  off = i; }
    else if (i < E1) { src = (const float4*)wq; off = i - E0; }
    else if (i < E2) { src = (const float4*)wk; off = i - E1; }
    else if (i < E3) { src = (const float4*)wv; off = i - E2; }
    else             { src = (const float4*)wo; off = i - E3; }
    float4 v = src[off];
    short4 o;
    o.x = f2bf(v.x); o.y = f2bf(v.y); o.z = f2bf(v.z); o.w = f2bf(v.w);
    ((short4*)out)[i] = o;
  }
}

// ---------------- 8-phase GEMM: C = A[M][K] * B[N][K]^T, BN=256, BK=64 -------
// 512 threads = 8 waves (2M x 4N). Per wave: (BM/2) x 64 output.
// LDS tiles [rows][64] bf16, 8x16B chunks/row, chunk-col ^= row&7 (T2).
// Schedule: 8 phases / 2 K-tiles, counted vmcnt(4) at ph3/ph7 (T3+T4),
// setprio around MFMA (T5). Stage-slot ledger verified (see analysis).
// MODE 0: single B (wo), f32 out. MODE 1: fused QKV, V written transposed.
template<int MODE, int BM>
__global__ __launch_bounds__(512, 2)
void gemm8_kernel(const short* __restrict__ A,
                  const short* __restrict__ Bq,
                  const short* __restrict__ Bk,
                  const short* __restrict__ Bv,
                  float* __restrict__ Cf,
                  short* __restrict__ Cq,
                  short* __restrict__ Ck,
                  short* __restrict__ Cv)
{
  constexpr int MREP = BM / 32;     // 16x16 M-fragments per wave
  constexpr int SPP  = MREP / 4;    // M-slabs per phase (2 for BM=256, 1 for 128)
  constexpr int AJ   = BM / 128;    // stage issues per A-half per wave
  constexpr int NT   = DM / 64;     // 64 K-tiles

  __shared__ short As[2][BM * 64];
  __shared__ short Bs[2][256 * 64];

  const int tid = threadIdx.x, lane = tid & 63, wid = tid >> 6;
  const int wr = wid >> 2, wn = wid & 3;
  const int cl = lane & 15, kh = lane >> 4;
  const int row0 = blockIdx.y * BM;
  const int col0 = blockIdx.x * 256;

  const short* Bmat; int bcol; int region = 0;
  if (MODE == 0) { Bmat = Bq; bcol = col0; }
  else {
    if (col0 < DM)            { Bmat = Bq; bcol = col0;            region = 0; }
    else if (col0 < DM + DKV) { Bmat = Bk; bcol = col0 - DM;       region = 1; }
    else                      { Bmat = Bv; bcol = col0 - DM - DKV; region = 2; }
  }

  f4_t acc[MREP][4];
  #pragma unroll
  for (int i = 0; i < MREP; i++)
    #pragma unroll
    for (int j = 0; j < 4; j++) { acc[i][j][0]=0.f; acc[i][j][1]=0.f; acc[i][j][2]=0.f; acc[i][j][3]=0.f; }

  // stage half h of K-tile kt into tile buffer T (inverse-swizzled source)
  auto STGA = [&](short* T, int h, int kt) {
    #pragma unroll
    for (int j = 0; j < AJ; ++j) {
      const int c = wid * (64 * AJ) + j * 64 + lane;   // [0, BM*4)
      const int row = h * (BM / 2) + (c >> 3), pcol = c & 7;
      const int lcol = pcol ^ (row & 7);
      async_copy16(&A[(size_t)(row0 + row) * DM + kt * 64 + lcol * 8],
                   &T[(h * (BM * 4) + c) * 8]);
    }
  };
  auto STGB = [&](short* T, int h, int kt) {
    #pragma unroll
    for (int j = 0; j < 2; ++j) {
      const int c = wid * 128 + j * 64 + lane;         // [0, 1024)
      const int row = h * 128 + (c >> 3), pcol = c & 7;
      const int lcol = pcol ^ (row & 7);
      async_copy16(&Bmat[(size_t)(bcol + row) * DM + kt * 64 + lcol * 8],
                   &T[(h * 1024 + c) * 8]);
    }
  };

  bf8_t bF[4][2];
  bf8_t aF[SPP][2];
  auto LDA = [&](const short* T, int ms0) {
    #pragma unroll
    for (int s = 0; s < SPP; ++s)
      #pragma unroll
      for (int q = 0; q < 2; ++q) {
        const int row = wr * (BM / 2) + (ms0 + s) * 16 + cl;
        const int pcol = (q * 4 + kh) ^ (row & 7);
        aF[s][q] = *(const bf8_t*)&T[(row * 8 + pcol) * 8];
      }
  };
  auto LDB = [&](const short* T) {
    #pragma unroll
    for (int n = 0; n < 4; ++n)
      #pragma unroll
      for (int q = 0; q < 2; ++q) {
        const int row = wn * 64 + n * 16 + cl;
        const int pcol = (q * 4 + kh) ^ (row & 7);
        bF[n][q] = *(const bf8_t*)&T[(row * 8 + pcol) * 8];
      }
  };

#define PHASE(TA, TB, PH, READB, STGSTMT, VMC)                                \
  {                                                                           \
    LDA(TA, (PH) * SPP);                                                      \
    if (READB) LDB(TB);                                                       \
    STGSTMT                                                                   \
    __builtin_amdgcn_s_barrier();                                             \
    asm volatile("s_waitcnt lgkmcnt(0)" ::: "memory");                        \
    __builtin_amdgcn_s_setprio(1);                                            \
    _Pragma("unroll")                                                         \
    for (int s_ = 0; s_ < SPP; ++s_) {                                        \
      _Pragma("unroll")                                                       \
      for (int n_ = 0; n_ < 4; ++n_) {                                        \
        _Pragma("unroll")                                                     \
        for (int q_ = 0; q_ < 2; ++q_)                                        \
          acc[(PH) * SPP + s_][n_] =                                          \
              mfma16(aF[s_][q_], bF[n_][q_], acc[(PH) * SPP + s_][n_]);       \
      }                                                                       \
    }                                                                         \
    __builtin_amdgcn_s_setprio(0);                                            \
    if (VMC) asm volatile("s_waitcnt vmcnt(4)" ::: "memory");                 \
    __builtin_amdgcn_s_barrier();                                             \
  }

  // prologue: T0 full + T1.B0,B1; wait T0 landed (leaves 4 loads in flight)
  STGB(Bs[0], 0, 0); STGB(Bs[0], 1, 0);
  STGA(As[0], 0, 0); STGA(As[0], 1, 0);
  STGB(Bs[1], 0, 1); STGB(Bs[1], 1, 1);
  asm volatile("s_waitcnt vmcnt(4)" ::: "memory");
  __builtin_amdgcn_s_barrier();

  for (int i = 0; i < NT / 2; ++i) {
    const int tA1 = 2 * i + 1;
    int t2 = 2 * i + 2; if (t2 > NT - 1) t2 = NT - 1;
    int t3 = 2 * i + 3; if (t3 > NT - 1) t3 = NT - 1;
    // phases 0-3: compute K-tile 2i from buf0
    PHASE(As[0], Bs[0], 0, true,  { STGA(As[1], 0, tA1); STGA(As[1], 1, tA1); }, false);
    PHASE(As[0], Bs[0], 1, false, { STGB(Bs[0], 0, t2); }, false);
    PHASE(As[0], Bs[0], 2, false, { STGB(Bs[0], 1, t2); }, false);
    PHASE(As[0], Bs[0], 3, false, { }, true);
    // phases 4-7: compute K-tile 2i+1 from buf1
    PHASE(As[1], Bs[1], 0, true,  { STGA(As[0], 0, t2); STGA(As[0], 1, t2); }, false);
    PHASE(As[1], Bs[1], 1, false, { STGB(Bs[1], 0, t3); }, false);
    PHASE(As[1], Bs[1], 2, false, { STGB(Bs[1], 1, t3); }, false);
    PHASE(As[1], Bs[1], 3, false, { }, true);
  }
#undef PHASE

  // epilogue: C layout col = lane&15, row = (lane>>4)*4 + reg
  const int rb = kh * 4;
  #pragma unroll
  for (int mi = 0; mi < MREP; mi++) {
    const int m0 = row0 + wr * (BM / 2) + mi * 16 + rb;
    #pragma unroll
    for (int ni = 0; ni < 4; ni++) {
      const int n = col0 + wn * 64 + ni * 16 + cl;
      if (MODE == 0) {
        #pragma unroll
        for (int r = 0; r < 4; r++) Cf[(size_t)(m0 + r) * DM + n] = acc[mi][ni][r];
      } else if (region == 0) {
        #pragma unroll
        for (int r = 0; r < 4; r++) Cq[(size_t)(m0 + r) * DM + n] = f2bf(acc[mi][ni][r]);
      } else if (region == 1) {
        const int nk = n - DM;
        #pragma unroll
        for (int r = 0; r < 4; r++) Ck[(size_t)(m0 + r) * DKV + nk] = f2bf(acc[mi][ni][r]);
      } else {
        const int nv = n - DM - DKV;   // 0..1023 = kv_head*128 + d
        short4 pk;
        pk.x = f2bf(acc[mi][ni][0]); pk.y = f2bf(acc[mi][ni][1]);
        pk.z = f2bf(acc[mi][ni][2]); pk.w = f2bf(acc[mi][ni][3]);
        *(short4*)&Cv[(size_t)nv * SEQ + m0] = pk;
      }
    }
  }
}

// ---------------- RoPE in-place on Q and K (bf16) ----------------
__global__ void rope_kernel(short* __restrict__ Qb, short* __restrict__ Kb,
                            const float* __restrict__ fcos, const float* __restrict__ fsin)
{
  const int NQP = SEQ * (DM / 2);
  const int NKP = SEQ * (DKV / 2);
  int idx = blockIdx.x * blockDim.x + threadIdx.x;
  if (idx >= NQP + NKP) return;
  short* T; int s, p, rowlen;
  if (idx < NQP) { T = Qb; s = idx >> 11; p = idx & 2047; rowlen = DM; }
  else { int j = idx - NQP; T = Kb; s = j >> 9; p = j & 511; rowlen = DKV; }
  const int h = p >> 6, i = p & 63;
  const float c  = fcos[s * 64 + i];
  const float sn = fsin[s * 64 + i];
  const size_t base = (size_t)s * rowlen + h * HD + 2 * i;
  const float e = bf2f(T[base]), o = bf2f(T[base + 1]);
  T[base]     = f2bf(e * c - o * sn);
  T[base + 1] = f2bf(e * sn + o * c);
}

// ---------------- Flash attention (causal, GQA, 32x32 swapped MFMA) ----------
__device__ __forceinline__ void flash_stage(const short* __restrict__ Kb,
                                            const short* __restrict__ Vt,
                                            short* Kl, short* Vl,
                                            int kv0, int hkv, int wid, int lane)
{
  #pragma unroll
  for (int i = 0; i < 4; ++i) {                 // K: 64 rows x 16 chunks
    int c = wid * 256 + i * 64 + lane;
    int row = c >> 4, pos = c & 15;
    int dc = pos ^ (row & 7);                   // inverse-swizzled source chunk
    async_copy16(&Kb[(size_t)(kv0 + row) * DKV + hkv * HD + dc * 8], &Kl[c * 8]);
  }
  #pragma unroll
  for (int i = 0; i < 4; ++i) {                 // V^T: 128 rows x 8 chunks
    int c = wid * 256 + i * 64 + lane;
    int row = c >> 3, pos = c & 7;
    int kc = pos ^ (row & 7);
    async_copy16(&Vt[(size_t)(hkv * HD + row) * SEQ + kv0 + kc * 8], &Vl[c * 8]);
  }
}

union U4B8 { uint32_t w[4]; bf8_t v; };

__device__ __forceinline__ void flash_compute(const short* __restrict__ Kl,
                                              const short* __restrict__ Vl,
                                              const bf8_t* qF, f16x* accO,
                                              float& m_run, float& l_run,
                                              int kv0, int qw0, int c31, int hi)
{
  const float scale = 0.08838834764831845f;  // 1/sqrt(128)

  // ---- S^T = K * Q^T : D[i=kv][j=q], lane holds q-col c31, 16 kv rows/half
  f16x accS[2];
  #pragma unroll
  for (int nu = 0; nu < 2; ++nu) {
    #pragma unroll
    for (int r = 0; r < 16; ++r) accS[nu][r] = 0.f;
  }
  #pragma unroll
  for (int nu = 0; nu < 2; ++nu) {
    const int row = nu * 32 + c31, rx = row & 7;
    #pragma unroll
    for (int s = 0; s < 8; ++s) {
      const int pos = (2 * s + hi) ^ rx;        // chunk 0..15 (XOR low 3 bits)
      bf8_t kf = *(const bf8_t*)&Kl[row * 128 + pos * 8];
      accS[nu] = mfma32(kf, qF[s], accS[nu]);
    }
  }

  // ---- causal mask (only near-diagonal tiles)
  if (kv0 + 63 > qw0) {
    const int q_abs = qw0 + c31;
    #pragma unroll
    for (int nu = 0; nu < 2; ++nu)
      #pragma unroll
      for (int r = 0; r < 16; ++r) {
        const int kv_abs = kv0 + 32 * nu + (r & 3) + 8 * (r >> 2) + 4 * hi;
        if (kv_abs > q_abs) accS[nu][r] = -3.0e38f;
      }
  }

  // ---- row max (31 local + xor32), defer-max rescale (THR=8)
  float rm = -3.0e38f;
  #pragma unroll
  for (int nu = 0; nu < 2; ++nu)
    #pragma unroll
    for (int r = 0; r < 16; ++r) rm = fmaxf(rm, accS[nu][r]);
  rm = fmaxf(rm, __shfl_xor(rm, 32));
  const float pmax = rm * scale;
  if (!__all(pmax - m_run <= 8.0f)) {
    const float mnew = fmaxf(m_run, pmax);
    const float corr = __expf(m_run - mnew);
    m_run = mnew;
    l_run *= corr;
    #pragma unroll
    for (int dt = 0; dt < 4; ++dt)
      #pragma unroll
      for (int r = 0; r < 16; ++r) accO[dt][r] *= corr;
  }

  // ---- P = exp(S*scale - m), pack quads to bf16 pairs, row-sum
  float tsum = 0.f;
  uint32_t u[8][2];
  #pragma unroll
  for (int m = 0; m < 8; ++m) {
    const int nu = m >> 2, rb = 4 * (m & 3);
    float p0 = __expf(fmaf(accS[nu][rb + 0], scale, -m_run));
    float p1 = __expf(fmaf(accS[nu][rb + 1], scale, -m_run));
    float p2 = __expf(fmaf(accS[nu][rb + 2], scale, -m_run));
    float p3 = __expf(fmaf(accS[nu][rb + 3], scale, -m_run));
    tsum += (p0 + p1) + (p2 + p3);
    u[m][0] = cvtpk(p0, p1);
    u[m][1] = cvtpk(p2, p3);
  }
  l_run += tsum + __shfl_xor(tsum, 32);

  // ---- build P^T B-fragments in-register (xor32 half exchange).
  bf8_t pa[4];
  #pragma unroll
  for (int ks = 0; ks < 4; ++ks) {
    const uint32_t a0 = u[2 * ks][0],     a1 = u[2 * ks][1];      // even group
    const uint32_t b0 = u[2 * ks + 1][0], b1 = u[2 * ks + 1][1];  // odd group
    const uint32_t mp0 = hi ? a0 : b0, mp1 = hi ? a1 : b1;        // presented
    const uint32_t s0 = __shfl_xor(mp0, 32), s1 = __shfl_xor(mp1, 32);
    U4B8 f;
    f.w[0] = hi ? s0 : a0;   // j=0,1
    f.w[1] = hi ? s1 : a1;   // j=2,3
    f.w[2] = hi ? b0 : s0;   // j=4,5
    f.w[3] = hi ? b1 : s1;   // j=6,7
    pa[ks] = f.v;
  }

  // ---- O^T += V^T * P^T : D[i=d][j=q]
  #pragma unroll
  for (int dt = 0; dt < 4; ++dt) {
    const int row = dt * 32 + c31, rx = row & 7;
    #pragma unroll
    for (int ks = 0; ks < 4; ++ks) {
      const int pos = (2 * ks + hi) ^ rx;       // chunk 0..7
      bf8_t vf = *(const bf8_t*)&Vl[row * 64 + pos * 8];
      accO[dt] = mfma32(vf, pa[ks], accO[dt]);
    }
  }
}

__global__ __launch_bounds__(256, 2)
void flash_kernel(const short* __restrict__ Qb,  // [SEQ][DM], roped
                  const short* __restrict__ Kb,  // [SEQ][DKV], roped
                  const short* __restrict__ Vt,  // [DKV][SEQ] transposed
                  short* __restrict__ Ob)        // [SEQ][DM]
{
  __shared__ short Kl0[64 * 128], Kl1[64 * 128];
  __shared__ short Vl0[128 * 64], Vl1[128 * 64];

  const int tid = threadIdx.x, lane = tid & 63, wid = tid >> 6;
  const int c31 = lane & 31, hi = lane >> 5;

  // balanced pairing: blocks b and b+256 -> same head, q-tiles p and 15-p
  const int b = blockIdx.x;
  const int pairid = b & 255, halfsel = b >> 8;
  const int h = pairid >> 3, p = pairid & 7;
  const int qt = halfsel ? (15 - p) : p;
  const int q0 = qt * 128;
  const int hkv = h >> 2;
  const int qw0 = q0 + wid * 32;

  // Q B-fragments in registers: Q[q=c31][k-slice s], 16B each
  bf8_t qF[8];
  {
    const size_t qb = (size_t)(qw0 + c31) * DM + h * HD + hi * 8;
    #pragma unroll
    for (int s = 0; s < 8; ++s) qF[s] = *(const bf8_t*)&Qb[qb + s * 16];
  }

  f16x accO[4];
  #pragma unroll
  for (int dt = 0; dt < 4; ++dt)
    #pragma unroll
    for (int r = 0; r < 16; ++r) accO[dt][r] = 0.f;
  float m_run = -INFINITY, l_run = 0.f;

  const int nt = (q0 >> 6) + 2;                 // even, 2..32

  flash_stage(Kb, Vt, Kl0, Vl0, 0, hkv, wid, lane);
  __syncthreads();
  for (int t = 0; t < nt; t += 2) {
    flash_stage(Kb, Vt, Kl1, Vl1, (t + 1) * 64, hkv, wid, lane);
    if (t * 64 <= qw0 + 31)
      flash_compute(Kl0, Vl0, qF, accO, m_run, l_run, t * 64, qw0, c31, hi);
    __syncthreads();
    if (t + 2 < nt) flash_stage(Kb, Vt, Kl0, Vl0, (t + 2) * 64, hkv, wid, lane);
    if ((t + 1) * 64 <= qw0 + 31)
      flash_compute(Kl1, Vl1, qF, accO, m_run, l_run, (t + 1) * 64, qw0, c31, hi);
    __syncthreads();
  }

  // ---- epilogue: normalize, transpose O^T->O via LDS (reuse K buffers)
  short* Ol = (wid < 2) ? &Kl0[wid * 4096] : &Kl1[(wid - 2) * 4096];
  const float oinv = 1.0f / l_run;
  #pragma unroll
  for (int dt = 0; dt < 4; ++dt)
    #pragma unroll
    for (int w = 0; w < 8; ++w) {
      const int r = 2 * w;
      const int d0 = (r & 3) + 8 * (r >> 2) + 4 * hi + dt * 32;
      const uint32_t pk = cvtpk(accO[dt][r] * oinv, accO[dt][r + 1] * oinv);
      const int pos = (d0 >> 3) ^ (c31 & 7);
      *(uint32_t*)&Ol[c31 * 128 + pos * 8 + (d0 & 7)] = pk;
    }
  __syncthreads();
  const int rowq = lane >> 1;
  #pragma unroll
  for (int i = 0; i < 8; ++i) {
    const int dc = (lane & 1) * 8 + i;
    const int pos = dc ^ (rowq & 7);
    int4 v = *(const int4*)&Ol[rowq * 128 + pos * 8];
    *(int4*)&Ob[(size_t)(q0 + wid * 32 + rowq) * DM + h * HD + dc * 8] = v;
  }
}

// ---------------- launch ----------------
extern "C" void kernel_launch(void* const* d_in, const int* in_sizes, int n_in,
                              void* d_out, int out_size, void* d_ws, size_t ws_size,
                              hipStream_t stream)
{
  const float* x    = (const float*)d_in[0];
  const float* fcos = (const float*)d_in[1];
  const float* fsin = (const float*)d_in[2];
  const float* wq   = (const float*)d_in[3];
  const float* wk   = (const float*)d_in[4];
  const float* wv   = (const float*)d_in[5];
  const float* wo   = (const float*)d_in[6];
  float* out = (float*)d_out;

  char* p = (char*)d_ws;
  short* xb  = (short*)p; p += (size_t)SEQ * DM * 2;
  short* wqb = (short*)p; p += (size_t)DM * DM * 2;
  short* wkb = (short*)p; p += (size_t)DKV * DM * 2;
  short* wvb = (short*)p; p += (size_t)DKV * DM * 2;
  short* wob = (short*)p; p += (size_t)DM * DM * 2;
  short* Qb  = (short*)p; p += (size_t)SEQ * DM * 2;
  short* Kb  = (short*)p; p += (size_t)SEQ * DKV * 2;
  short* Vt  = (short*)p; p += (size_t)DKV * SEQ * 2;
  short* Ab  = (short*)p; p += (size_t)SEQ * DM * 2;

  cvt_all_kernel<<<2048, 256, 0, stream>>>(x, wq, wk, wv, wo, xb);

  gemm8_kernel<1, 256><<<dim3(24, 8), 512, 0, stream>>>(xb, wqb, wkb, wvb,
                                                        nullptr, Qb, Kb, Vt);
  rope_kernel<<<20480, 256, 0, stream>>>(Qb, Kb, fcos, fsin);
  flash_kernel<<<512, 256, 0, stream>>>(Qb, Kb, Vt, Ab);
  gemm8_kernel<0, 128><<<dim3(16, 16), 512, 0, stream>>>(Ab, wob, nullptr, nullptr,
                                                         out, nullptr, nullptr, nullptr);
}

// Round 5
// 278.058 us; speedup vs baseline: 1.6506x; 1.0423x over previous
//
#include <hip/hip_runtime.h>
#include <hip/hip_bf16.h>
#include <stdint.h>

#define SEQ   2048
#define DM    4096
#define NH    32
#define NKV   8
#define HD    128
#define DKV   1024   // NKV*HD

typedef __attribute__((ext_vector_type(8))) short bf8_t;   // 8 bf16 (4 VGPR)
typedef __attribute__((ext_vector_type(4))) float f4_t;
typedef __attribute__((ext_vector_type(16))) float f16x;

__device__ __forceinline__ short f2bf(float f) {
  union { float f; uint32_t u; } v; v.f = f;
  uint32_t r = v.u + 0x7FFFu + ((v.u >> 16) & 1u);
  return (short)(r >> 16);
}
__device__ __forceinline__ float bf2f(short s) {
  union { uint32_t u; float f; } v; v.u = ((uint32_t)(uint16_t)s) << 16;
  return v.f;
}
__device__ __forceinline__ uint32_t cvtpk(float lo, float hi) {
  uint32_t r;
  asm("v_cvt_pk_bf16_f32 %0, %1, %2" : "=v"(r) : "v"(lo), "v"(hi));
  return r;
}

// CK-style global->LDS async copy, 16B per lane (lds addr must be lane-linear)
__device__ __forceinline__ void async_copy16(const void* gsrc, void* ldst) {
  auto g = reinterpret_cast<const __attribute__((address_space(1))) uint32_t*>(
      reinterpret_cast<uintptr_t>(gsrc));
  auto l = reinterpret_cast<__attribute__((address_space(3))) uint32_t*>(
      reinterpret_cast<uintptr_t>(ldst));
  __builtin_amdgcn_global_load_lds(g, l, 16, 0, 0);
}

__device__ __forceinline__ f4_t mfma16(bf8_t a, bf8_t b, f4_t c) {
  return __builtin_amdgcn_mfma_f32_16x16x32_bf16(a, b, c, 0, 0, 0);
}
__device__ __forceinline__ f16x mfma32(bf8_t a, bf8_t b, f16x c) {
  return __builtin_amdgcn_mfma_f32_32x32x16_bf16(a, b, c, 0, 0, 0);
}

template<int N> __device__ __forceinline__ void vmwait();
template<> __device__ __forceinline__ void vmwait<3>() {
  asm volatile("s_waitcnt vmcnt(3)" ::: "memory");
}
template<> __device__ __forceinline__ void vmwait<4>() {
  asm volatile("s_waitcnt vmcnt(4)" ::: "memory");
}

// ---------------- fused f32 -> bf16 convert (x, wq, wk, wv, wo) ----------------
// Output bf16 regions are contiguous at d_ws start in this exact order;
// wq/wk/wv contiguity => one [6144][4096] QKV weight matrix for the GEMM.
__global__ void cvt_all_kernel(const float* __restrict__ x,
                               const float* __restrict__ wq,
                               const float* __restrict__ wk,
                               const float* __restrict__ wv,
                               const float* __restrict__ wo,
                               short* __restrict__ out)
{
  const int E0 = SEQ * DM / 4;
  const int E1 = E0 + DM * DM / 4;
  const int E2 = E1 + DKV * DM / 4;
  const int E3 = E2 + DKV * DM / 4;
  const int E4 = E3 + DM * DM / 4;
  const int stride = gridDim.x * blockDim.x;
  for (int i = blockIdx.x * blockDim.x + threadIdx.x; i < E4; i += stride) {
    const float4* src; int off;
    if (i < E0)      { src = (const float4*)x;  off = i; }
    else if (i < E1) { src = (const float4*)wq; off = i - E0; }
    else if (i < E2) { src = (const float4*)wk; off = i - E1; }
    else if (i < E3) { src = (const float4*)wv; off = i - E2; }
    else             { src = (const float4*)wo; off = i - E3; }
    float4 v = src[off];
    short4 o;
    o.x = f2bf(v.x); o.y = f2bf(v.y); o.z = f2bf(v.z); o.w = f2bf(v.w);
    ((short4*)out)[i] = o;
  }
}

// ---------------- 8-phase GEMM: C = A[M][K] * B[N][K]^T, BK=64 ---------------
// 512 threads = 8 waves (2M x 4N). B staged in 64-row slabs (1 gload/wave).
// LDS [rows][64] bf16, 8x16B chunks/row, chunk-col ^= row&7 (T2, both sides).
// 8 phases / 2 K-tiles, counted vmcnt(SB) at ph3/ph7 (T3+T4), setprio (T5).
// MODE 0: f32 out. MODE 1: fused QKV over contiguous W[6144][4096]; per-column
// region routing (Q | K | V-transposed) in the epilogue.
template<int MODE, int BM, int BN>
__global__ __launch_bounds__(512, 2)
void gemm8_kernel(const short* __restrict__ A,
                  const short* __restrict__ Bw,
                  float* __restrict__ Cf,
                  short* __restrict__ Cq,
                  short* __restrict__ Ck,
                  short* __restrict__ Cv)
{
  constexpr int MREP = BM / 32;     // 16x16 M-fragments per wave
  constexpr int SPP  = MREP / 4;    // M-slabs per phase
  constexpr int AJ   = BM / 128;    // stage issues per A-half per wave
  constexpr int SB   = BN / 64;     // B slabs (= N-fragments per wave)
  constexpr int NT   = DM / 64;     // K-tiles

  __shared__ short As[2][BM * 64];
  __shared__ short Bs[2][BN * 64];

  const int tid = threadIdx.x, lane = tid & 63, wid = tid >> 6;
  const int wr = wid >> 2, wn = wid & 3;
  const int cl = lane & 15, kh = lane >> 4;
  const int row0 = blockIdx.y * BM;
  const int col0 = blockIdx.x * BN;

  f4_t acc[MREP][SB];
  #pragma unroll
  for (int i = 0; i < MREP; i++)
    #pragma unroll
    for (int j = 0; j < SB; j++) { acc[i][j][0]=0.f; acc[i][j][1]=0.f; acc[i][j][2]=0.f; acc[i][j][3]=0.f; }

  // stage half h (A) / slab sl (B) of K-tile kt (inverse-swizzled source)
  auto STGA = [&](short* T, int h, int kt) {
    #pragma unroll
    for (int j = 0; j < AJ; ++j) {
      const int c = wid * (64 * AJ) + j * 64 + lane;   // [0, BM*4)
      const int row = h * (BM / 2) + (c >> 3), pcol = c & 7;
      const int lcol = pcol ^ (row & 7);
      async_copy16(&A[(size_t)(row0 + row) * DM + kt * 64 + lcol * 8],
                   &T[(h * (BM * 4) + c) * 8]);
    }
  };
  auto STGB = [&](short* T, int sl, int kt) {
    const int c = wid * 64 + lane;                     // [0, 512)
    const int row = sl * 64 + (c >> 3), pcol = c & 7;
    const int lcol = pcol ^ (row & 7);
    async_copy16(&Bw[(size_t)(col0 + row) * DM + kt * 64 + lcol * 8],
                 &T[(sl * 512 + c) * 8]);
  };

  bf8_t bF[SB][2];
  bf8_t aF[SPP][2];
  auto LDA = [&](const short* T, int ms0) {
    #pragma unroll
    for (int s = 0; s < SPP; ++s)
      #pragma unroll
      for (int q = 0; q < 2; ++q) {
        const int row = wr * (BM / 2) + (ms0 + s) * 16 + cl;
        const int pcol = (q * 4 + kh) ^ (row & 7);
        aF[s][q] = *(const bf8_t*)&T[(row * 8 + pcol) * 8];
      }
  };
  auto LDB = [&](const short* T) {
    #pragma unroll
    for (int n = 0; n < SB; ++n)
      #pragma unroll
      for (int q = 0; q < 2; ++q) {
        const int row = wn * (16 * SB) + n * 16 + cl;
        const int pcol = (q * 4 + kh) ^ (row & 7);
        bF[n][q] = *(const bf8_t*)&T[(row * 8 + pcol) * 8];
      }
  };

#define PHASE(TA, TB, PH, READB, STGSTMT, VMC)                                \
  {                                                                           \
    LDA(TA, (PH) * SPP);                                                      \
    if (READB) LDB(TB);                                                       \
    STGSTMT                                                                   \
    __builtin_amdgcn_s_barrier();                                             \
    asm volatile("s_waitcnt lgkmcnt(0)" ::: "memory");                        \
    __builtin_amdgcn_s_setprio(1);                                            \
    _Pragma("unroll")                                                         \
    for (int s_ = 0; s_ < SPP; ++s_) {                                        \
      _Pragma("unroll")                                                       \
      for (int n_ = 0; n_ < SB; ++n_) {                                       \
        _Pragma("unroll")                                                     \
        for (int q_ = 0; q_ < 2; ++q_)                                        \
          acc[(PH) * SPP + s_][n_] =                                          \
              mfma16(aF[s_][q_], bF[n_][q_], acc[(PH) * SPP + s_][n_]);       \
      }                                                                       \
    }                                                                         \
    __builtin_amdgcn_s_setprio(0);                                            \
    if (VMC) vmwait<SB>();                                                    \
    __builtin_amdgcn_s_barrier();                                             \
  }

  // prologue: B0 all slabs + A0 full + B1 all slabs; wait tile0 landed
  #pragma unroll
  for (int sl = 0; sl < SB; ++sl) STGB(Bs[0], sl, 0);
  STGA(As[0], 0, 0); STGA(As[0], 1, 0);
  #pragma unroll
  for (int sl = 0; sl < SB; ++sl) STGB(Bs[1], sl, 1);
  vmwait<SB>();
  __builtin_amdgcn_s_barrier();

  for (int i = 0; i < NT / 2; ++i) {
    const int tA1 = 2 * i + 1;
    int t2 = 2 * i + 2; if (t2 > NT - 1) t2 = NT - 1;
    int t3 = 2 * i + 3; if (t3 > NT - 1) t3 = NT - 1;
    if constexpr (SB == 4) {
      PHASE(As[0], Bs[0], 0, true,  { STGA(As[1], 0, tA1); STGA(As[1], 1, tA1); }, false);
      PHASE(As[0], Bs[0], 1, false, { STGB(Bs[0], 0, t2); STGB(Bs[0], 1, t2); }, false);
      PHASE(As[0], Bs[0], 2, false, { STGB(Bs[0], 2, t2); STGB(Bs[0], 3, t2); }, false);
      PHASE(As[0], Bs[0], 3, false, { }, true);
      PHASE(As[1], Bs[1], 0, true,  { STGA(As[0], 0, t2); STGA(As[0], 1, t2); }, false);
      PHASE(As[1], Bs[1], 1, false, { STGB(Bs[1], 0, t3); STGB(Bs[1], 1, t3); }, false);
      PHASE(As[1], Bs[1], 2, false, { STGB(Bs[1], 2, t3); STGB(Bs[1], 3, t3); }, false);
      PHASE(As[1], Bs[1], 3, false, { }, true);
    } else {   // SB == 3
      PHASE(As[0], Bs[0], 0, true,  { STGA(As[1], 0, tA1); STGA(As[1], 1, tA1); }, false);
      PHASE(As[0], Bs[0], 1, false, { STGB(Bs[0], 0, t2); }, false);
      PHASE(As[0], Bs[0], 2, false, { STGB(Bs[0], 1, t2); }, false);
      PHASE(As[0], Bs[0], 3, false, { STGB(Bs[0], 2, t2); }, true);
      PHASE(As[1], Bs[1], 0, true,  { STGA(As[0], 0, t2); STGA(As[0], 1, t2); }, false);
      PHASE(As[1], Bs[1], 1, false, { STGB(Bs[1], 0, t3); }, false);
      PHASE(As[1], Bs[1], 2, false, { STGB(Bs[1], 1, t3); }, false);
      PHASE(As[1], Bs[1], 3, false, { STGB(Bs[1], 2, t3); }, true);
    }
  }
#undef PHASE

  // epilogue: C layout col = lane&15, row = (lane>>4)*4 + reg
  const int rb = kh * 4;
  #pragma unroll
  for (int mi = 0; mi < MREP; mi++) {
    const int m0 = row0 + wr * (BM / 2) + mi * 16 + rb;
    #pragma unroll
    for (int ni = 0; ni < SB; ni++) {
      const int n = col0 + wn * (16 * SB) + ni * 16 + cl;
      if (MODE == 0) {
        #pragma unroll
        for (int r = 0; r < 4; r++) Cf[(size_t)(m0 + r) * DM + n] = acc[mi][ni][r];
      } else if (n < DM) {
        #pragma unroll
        for (int r = 0; r < 4; r++) Cq[(size_t)(m0 + r) * DM + n] = f2bf(acc[mi][ni][r]);
      } else if (n < DM + DKV) {
        const int nk = n - DM;
        #pragma unroll
        for (int r = 0; r < 4; r++) Ck[(size_t)(m0 + r) * DKV + nk] = f2bf(acc[mi][ni][r]);
      } else {
        const int nv = n - DM - DKV;   // 0..1023 = kv_head*128 + d
        short4 pk;
        pk.x = f2bf(acc[mi][ni][0]); pk.y = f2bf(acc[mi][ni][1]);
        pk.z = f2bf(acc[mi][ni][2]); pk.w = f2bf(acc[mi][ni][3]);
        *(short4*)&Cv[(size_t)nv * SEQ + m0] = pk;
      }
    }
  }
}

// ---------------- RoPE in-place on Q and K (bf16) ----------------
__global__ void rope_kernel(short* __restrict__ Qb, short* __restrict__ Kb,
                            const float* __restrict__ fcos, const float* __restrict__ fsin)
{
  const int NQP = SEQ * (DM / 2);
  const int NKP = SEQ * (DKV / 2);
  int idx = blockIdx.x * blockDim.x + threadIdx.x;
  if (idx >= NQP + NKP) return;
  short* T; int s, p, rowlen;
  if (idx < NQP) { T = Qb; s = idx >> 11; p = idx & 2047; rowlen = DM; }
  else { int j = idx - NQP; T = Kb; s = j >> 9; p = j & 511; rowlen = DKV; }
  const int h = p >> 6, i = p & 63;
  const float c  = fcos[s * 64 + i];
  const float sn = fsin[s * 64 + i];
  const size_t base = (size_t)s * rowlen + h * HD + 2 * i;
  const float e = bf2f(T[base]), o = bf2f(T[base + 1]);
  T[base]     = f2bf(e * c - o * sn);
  T[base + 1] = f2bf(e * sn + o * c);
}

// ---------------- Flash attention (causal, GQA, 32x32 swapped MFMA) ----------
__device__ __forceinline__ void flash_stage(const short* __restrict__ Kb,
                                            const short* __restrict__ Vt,
                                            short* Kl, short* Vl,
                                            int kv0, int hkv, int wid, int lane)
{
  #pragma unroll
  for (int i = 0; i < 4; ++i) {                 // K: 64 rows x 16 chunks
    int c = wid * 256 + i * 64 + lane;
    int row = c >> 4, pos = c & 15;
    int dc = pos ^ (row & 7);                   // inverse-swizzled source chunk
    async_copy16(&Kb[(size_t)(kv0 + row) * DKV + hkv * HD + dc * 8], &Kl[c * 8]);
  }
  #pragma unroll
  for (int i = 0; i < 4; ++i) {                 // V^T: 128 rows x 8 chunks
    int c = wid * 256 + i * 64 + lane;
    int row = c >> 3, pos = c & 7;
    int kc = pos ^ (row & 7);
    async_copy16(&Vt[(size_t)(hkv * HD + row) * SEQ + kv0 + kc * 8], &Vl[c * 8]);
  }
}

union U4B8 { uint32_t w[4]; bf8_t v; };

__device__ __forceinline__ void flash_compute(const short* __restrict__ Kl,
                                              const short* __restrict__ Vl,
                                              const bf8_t* qF, f16x* accO,
                                              float& m_run, float& l_run,
                                              int kv0, int qw0, int c31, int hi)
{
  const float scale = 0.08838834764831845f;  // 1/sqrt(128)

  f16x accS[2];
  #pragma unroll
  for (int nu = 0; nu < 2; ++nu) {
    #pragma unroll
    for (int r = 0; r < 16; ++r) accS[nu][r] = 0.f;
  }
  #pragma unroll
  for (int nu = 0; nu < 2; ++nu) {
    const int row = nu * 32 + c31, rx = row & 7;
    #pragma unroll
    for (int s = 0; s < 8; ++s) {
      const int pos = (2 * s + hi) ^ rx;
      bf8_t kf = *(const bf8_t*)&Kl[row * 128 + pos * 8];
      accS[nu] = mfma32(kf, qF[s], accS[nu]);
    }
  }

  if (kv0 + 63 > qw0) {
    const int q_abs = qw0 + c31;
    #pragma unroll
    for (int nu = 0; nu < 2; ++nu)
      #pragma unroll
      for (int r = 0; r < 16; ++r) {
        const int kv_abs = kv0 + 32 * nu + (r & 3) + 8 * (r >> 2) + 4 * hi;
        if (kv_abs > q_abs) accS[nu][r] = -3.0e38f;
      }
  }

  float rm = -3.0e38f;
  #pragma unroll
  for (int nu = 0; nu < 2; ++nu)
    #pragma unroll
    for (int r = 0; r < 16; ++r) rm = fmaxf(rm, accS[nu][r]);
  rm = fmaxf(rm, __shfl_xor(rm, 32));
  const float pmax = rm * scale;
  if (!__all(pmax - m_run <= 8.0f)) {
    const float mnew = fmaxf(m_run, pmax);
    const float corr = __expf(m_run - mnew);
    m_run = mnew;
    l_run *= corr;
    #pragma unroll
    for (int dt = 0; dt < 4; ++dt)
      #pragma unroll
      for (int r = 0; r < 16; ++r) accO[dt][r] *= corr;
  }

  float tsum = 0.f;
  uint32_t u[8][2];
  #pragma unroll
  for (int m = 0; m < 8; ++m) {
    const int nu = m >> 2, rb = 4 * (m & 3);
    float p0 = __expf(fmaf(accS[nu][rb + 0], scale, -m_run));
    float p1 = __expf(fmaf(accS[nu][rb + 1], scale, -m_run));
    float p2 = __expf(fmaf(accS[nu][rb + 2], scale, -m_run));
    float p3 = __expf(fmaf(accS[nu][rb + 3], scale, -m_run));
    tsum += (p0 + p1) + (p2 + p3);
    u[m][0] = cvtpk(p0, p1);
    u[m][1] = cvtpk(p2, p3);
  }
  l_run += tsum + __shfl_xor(tsum, 32);

  bf8_t pa[4];
  #pragma unroll
  for (int ks = 0; ks < 4; ++ks) {
    const uint32_t a0 = u[2 * ks][0],     a1 = u[2 * ks][1];
    const uint32_t b0 = u[2 * ks + 1][0], b1 = u[2 * ks + 1][1];
    const uint32_t mp0 = hi ? a0 : b0, mp1 = hi ? a1 : b1;
    const uint32_t s0 = __shfl_xor(mp0, 32), s1 = __shfl_xor(mp1, 32);
    U4B8 f;
    f.w[0] = hi ? s0 : a0;
    f.w[1] = hi ? s1 : a1;
    f.w[2] = hi ? b0 : s0;
    f.w[3] = hi ? b1 : s1;
    pa[ks] = f.v;
  }

  #pragma unroll
  for (int dt = 0; dt < 4; ++dt) {
    const int row = dt * 32 + c31, rx = row & 7;
    #pragma unroll
    for (int ks = 0; ks < 4; ++ks) {
      const int pos = (2 * ks + hi) ^ rx;
      bf8_t vf = *(const bf8_t*)&Vl[row * 64 + pos * 8];
      accO[dt] = mfma32(vf, pa[ks], accO[dt]);
    }
  }
}

__global__ __launch_bounds__(256, 2)
void flash_kernel(const short* __restrict__ Qb,
                  const short* __restrict__ Kb,
                  const short* __restrict__ Vt,
                  short* __restrict__ Ob)
{
  __shared__ short Kl0[64 * 128], Kl1[64 * 128];
  __shared__ short Vl0[128 * 64], Vl1[128 * 64];

  const int tid = threadIdx.x, lane = tid & 63, wid = tid >> 6;
  const int c31 = lane & 31, hi = lane >> 5;

  const int b = blockIdx.x;
  const int pairid = b & 255, halfsel = b >> 8;
  const int h = pairid >> 3, p = pairid & 7;
  const int qt = halfsel ? (15 - p) : p;
  const int q0 = qt * 128;
  const int hkv = h >> 2;
  const int qw0 = q0 + wid * 32;

  bf8_t qF[8];
  {
    const size_t qb = (size_t)(qw0 + c31) * DM + h * HD + hi * 8;
    #pragma unroll
    for (int s = 0; s < 8; ++s) qF[s] = *(const bf8_t*)&Qb[qb + s * 16];
  }

  f16x accO[4];
  #pragma unroll
  for (int dt = 0; dt < 4; ++dt)
    #pragma unroll
    for (int r = 0; r < 16; ++r) accO[dt][r] = 0.f;
  float m_run = -INFINITY, l_run = 0.f;

  const int nt = (q0 >> 6) + 2;

  flash_stage(Kb, Vt, Kl0, Vl0, 0, hkv, wid, lane);
  __syncthreads();
  for (int t = 0; t < nt; t += 2) {
    flash_stage(Kb, Vt, Kl1, Vl1, (t + 1) * 64, hkv, wid, lane);
    if (t * 64 <= qw0 + 31)
      flash_compute(Kl0, Vl0, qF, accO, m_run, l_run, t * 64, qw0, c31, hi);
    __syncthreads();
    if (t + 2 < nt) flash_stage(Kb, Vt, Kl0, Vl0, (t + 2) * 64, hkv, wid, lane);
    if ((t + 1) * 64 <= qw0 + 31)
      flash_compute(Kl1, Vl1, qF, accO, m_run, l_run, (t + 1) * 64, qw0, c31, hi);
    __syncthreads();
  }

  short* Ol = (wid < 2) ? &Kl0[wid * 4096] : &Kl1[(wid - 2) * 4096];
  const float oinv = 1.0f / l_run;
  #pragma unroll
  for (int dt = 0; dt < 4; ++dt)
    #pragma unroll
    for (int w = 0; w < 8; ++w) {
      const int r = 2 * w;
      const int d0 = (r & 3) + 8 * (r >> 2) + 4 * hi + dt * 32;
      const uint32_t pk = cvtpk(accO[dt][r] * oinv, accO[dt][r + 1] * oinv);
      const int pos = (d0 >> 3) ^ (c31 & 7);
      *(uint32_t*)&Ol[c31 * 128 + pos * 8 + (d0 & 7)] = pk;
    }
  __syncthreads();
  const int rowq = lane >> 1;
  #pragma unroll
  for (int i = 0; i < 8; ++i) {
    const int dc = (lane & 1) * 8 + i;
    const int pos = dc ^ (rowq & 7);
    int4 v = *(const int4*)&Ol[rowq * 128 + pos * 8];
    *(int4*)&Ob[(size_t)(q0 + wid * 32 + rowq) * DM + h * HD + dc * 8] = v;
  }
}

// ---------------- launch ----------------
extern "C" void kernel_launch(void* const* d_in, const int* in_sizes, int n_in,
                              void* d_out, int out_size, void* d_ws, size_t ws_size,
                              hipStream_t stream)
{
  const float* x    = (const float*)d_in[0];
  const float* fcos = (const float*)d_in[1];
  const float* fsin = (const float*)d_in[2];
  const float* wq   = (const float*)d_in[3];
  const float* wk   = (const float*)d_in[4];
  const float* wv   = (const float*)d_in[5];
  const float* wo   = (const float*)d_in[6];
  float* out = (float*)d_out;

  char* p = (char*)d_ws;
  short* xb  = (short*)p; p += (size_t)SEQ * DM * 2;
  short* wqb = (short*)p; p += (size_t)DM * DM * 2;    // wqb..wvb contiguous = W[6144][4096]
  short* wkb = (short*)p; p += (size_t)DKV * DM * 2;
  short* wvb = (short*)p; p += (size_t)DKV * DM * 2;
  short* wob = (short*)p; p += (size_t)DM * DM * 2;
  short* Qb  = (short*)p; p += (size_t)SEQ * DM * 2;
  short* Kb  = (short*)p; p += (size_t)SEQ * DKV * 2;
  short* Vt  = (short*)p; p += (size_t)DKV * SEQ * 2;
  short* Ab  = (short*)p; p += (size_t)SEQ * DM * 2;
  (void)wkb; (void)wvb;

  cvt_all_kernel<<<2048, 256, 0, stream>>>(x, wq, wk, wv, wo, xb);

  gemm8_kernel<1, 256, 192><<<dim3(32, 8), 512, 0, stream>>>(xb, wqb,
                                                             nullptr, Qb, Kb, Vt);
  rope_kernel<<<20480, 256, 0, stream>>>(Qb, Kb, fcos, fsin);
  flash_kernel<<<512, 256, 0, stream>>>(Qb, Kb, Vt, Ab);
  gemm8_kernel<0, 128, 256><<<dim3(16, 16), 512, 0, stream>>>(Ab, wob,
                                                              out, nullptr, nullptr, nullptr);
}